// Round 20
// baseline (151.591 us; speedup 1.0000x reference)
//
#include <hip/hip_runtime.h>

// MoE-LoRA top-1 dispatch — R14 structure + bf16 x-handoff (split-job prep):
//  prep: [0,512) pool partials (pure read) ; [512,1536) A/B frag-pack ;
//        [1536,2048) x->bf16 cvt (re-reads x, L2/L3-hot; 16B packed stores)
//  -> router_h -> router_finish -> xrout (xbf@A^T -> in-LDS xr -> @B^T -> out)
constexpr int B_ = 4, S_ = 2048, D_ = 4096, E_ = 4, R_ = 64, OUT_ = 4096;
constexpr int NMOD = 4, NREG = 3, HID_ = 128;
constexpr int RIN_ = D_ + NMOD + NREG;      // 4103
constexpr float SCALING_ = 2.0f;            // alpha/rank
constexpr int P_   = 128;                   // pool strips of 16 rows
constexpr int KC_  = 33;                    // router k-chunks of 128 (33*128 >= 4103)

// ws layout (float units)
constexpr size_t WS_PP    = 0;                                     // P_*B*D f32 pool partials
constexpr size_t WS_HACC2 = WS_PP + (size_t)P_ * B_ * D_;          // B*KC_*HID f32
constexpr size_t WS_TOP   = WS_HACC2 + B_ * KC_ * HID_;            // B ints
constexpr size_t WS_APK   = WS_TOP + 16;                           // E*R*D bf16 frag-packed
constexpr size_t WS_BPK   = WS_APK + (size_t)E_ * R_ * D_ / 2;     // E*OUT*R bf16 frag-packed
constexpr size_t WS_XBF   = WS_BPK + (size_t)E_ * OUT_ * R_ / 2;   // B*S*D bf16 linear

using short8 = __attribute__((ext_vector_type(8))) short;
using f32x4  = __attribute__((ext_vector_type(4))) float;
union frag_u { int4 i4; short8 s8; };

__device__ inline unsigned short f2bf(float f) {  // RNE fp32 -> bf16
    unsigned u = __float_as_uint(f);
    unsigned r = u + 0x7FFFu + ((u >> 16) & 1u);
    return (unsigned short)(r >> 16);
}
__device__ inline unsigned pk2(float a, float b) { // two bf16 in one dword
    return (unsigned)f2bf(a) | ((unsigned)f2bf(b) << 16);
}

// One launch, four barrier-free jobs:
//  [0,512):     pool partials, strip = bx>>2 (16 rows), b = bx&3   (pure read)
//  [512,1024):  Apack[((e*128+ks)*4+n)*64+l][j] = A[e][n*16+(l&15)][ks*32+(l>>4)*8+j]
//  [1024,1536): Bpack[((e*256+nt)*2+kk)*64+l][j] = B[e][nt*16+(l&15)][kk*32+(l>>4)*8+j]
//  [1536,2048): x -> bf16 (same strip mapping as pool job; 16B packed stores)
__global__ __launch_bounds__(256) void prep_kernel(const float* __restrict__ x,
                                                   const float* __restrict__ A,
                                                   const float* __restrict__ Bw,
                                                   float* __restrict__ pp,
                                                   ushort* __restrict__ Apk,
                                                   ushort* __restrict__ Bpk,
                                                   ushort* __restrict__ xbf) {
    int bx = blockIdx.x, t = threadIdx.x;
    if (bx < 512) {
        int strip = bx >> 2, b = bx & 3;
        const float4* xp = (const float4*)(x + ((size_t)b * S_ + strip * 16) * D_);
        float4 a0 = {0,0,0,0}, a1 = {0,0,0,0}, a2 = {0,0,0,0}, a3 = {0,0,0,0};
#pragma unroll 4
        for (int r = 0; r < 16; ++r) {
            float4 v0 = xp[(size_t)r * 1024 + t];
            float4 v1 = xp[(size_t)r * 1024 + 256 + t];
            float4 v2 = xp[(size_t)r * 1024 + 512 + t];
            float4 v3 = xp[(size_t)r * 1024 + 768 + t];
            a0.x += v0.x; a0.y += v0.y; a0.z += v0.z; a0.w += v0.w;
            a1.x += v1.x; a1.y += v1.y; a1.z += v1.z; a1.w += v1.w;
            a2.x += v2.x; a2.y += v2.y; a2.z += v2.z; a2.w += v2.w;
            a3.x += v3.x; a3.y += v3.y; a3.z += v3.z; a3.w += v3.w;
        }
        float* ppb = pp + ((size_t)strip * B_ + b) * D_;
        *(float4*)&ppb[(t)       * 4] = a0;
        *(float4*)&ppb[(256 + t) * 4] = a1;
        *(float4*)&ppb[(512 + t) * 4] = a2;
        *(float4*)&ppb[(768 + t) * 4] = a3;
    } else if (bx < 1024) {
        int idx = (bx - 512) * 256 + t;              // E*128*4*64 = 131072
        int l = idx & 63, n = (idx >> 6) & 3, ks = (idx >> 8) & 127, e = idx >> 15;
        const float* src = A + ((size_t)e * R_ + n * 16 + (l & 15)) * D_
                             + ks * 32 + (l >> 4) * 8;
        float4 v0 = *(const float4*)(src);
        float4 v1 = *(const float4*)(src + 4);
        ushort* dst = Apk + (size_t)idx * 8;
        *(ushort4*)(dst)     = make_ushort4(f2bf(v0.x), f2bf(v0.y), f2bf(v0.z), f2bf(v0.w));
        *(ushort4*)(dst + 4) = make_ushort4(f2bf(v1.x), f2bf(v1.y), f2bf(v1.z), f2bf(v1.w));
    } else if (bx < 1536) {
        int idx = (bx - 1024) * 256 + t;             // E*256*2*64 = 131072
        int l = idx & 63, kk = (idx >> 6) & 1, nt = (idx >> 7) & 255, e = idx >> 15;
        const float* src = Bw + ((size_t)e * OUT_ + nt * 16 + (l & 15)) * R_
                              + kk * 32 + (l >> 4) * 8;
        float4 v0 = *(const float4*)(src);
        float4 v1 = *(const float4*)(src + 4);
        ushort* dst = Bpk + (size_t)idx * 8;
        *(ushort4*)(dst)     = make_ushort4(f2bf(v0.x), f2bf(v0.y), f2bf(v0.z), f2bf(v0.w));
        *(ushort4*)(dst + 4) = make_ushort4(f2bf(v1.x), f2bf(v1.y), f2bf(v1.z), f2bf(v1.w));
    } else {
        int j2 = bx - 1536;                          // x -> bf16, strips shared with pool job
        int strip = j2 >> 2, b = j2 & 3;
        const float4* xp = (const float4*)(x + ((size_t)b * S_ + strip * 16) * D_);
        int4* xo = (int4*)(xbf + ((size_t)b * S_ + strip * 16) * D_);
#pragma unroll 4
        for (int r = 0; r < 16; ++r) {
#pragma unroll
            for (int h = 0; h < 2; ++h) {
                float4 va = xp[(size_t)r * 1024 + h * 512 + 2 * t];
                float4 vb = xp[(size_t)r * 1024 + h * 512 + 2 * t + 1];
                int4 o = make_int4(pk2(va.x, va.y), pk2(va.z, va.w),
                                   pk2(vb.x, vb.y), pk2(vb.z, vb.w));
                xo[(size_t)r * 512 + h * 256 + t] = o;   // 512 int4/row, 256/half
            }
        }
    }
}

// hacc2[b][kc][h] = sum over chunk's 128 k-rows of router_in[k]*w1[k][h]
__global__ __launch_bounds__(256) void router_h_kernel(const float* __restrict__ pp,
                                                       const float* __restrict__ rel,
                                                       const float* __restrict__ reg,
                                                       const float* __restrict__ w1,
                                                       float* __restrict__ hacc2) {
    __shared__ float rin[128];
    __shared__ float red[256];
    int b = blockIdx.x, kc = blockIdx.y;
    int t = threadIdx.x;
    int k0 = kc * 128;
    {
        int k = k0 + (t & 127), half = t >> 7;
        float s = 0.f;
        if (k < D_) {
            for (int pi = half * 64; pi < half * 64 + 64; ++pi)
                s += pp[((size_t)pi * B_ + b) * D_ + k];
        }
        red[t] = s;
    }
    __syncthreads();
    if (t < 128) {
        int k = k0 + t;
        float v = 0.f;
        if (k < D_)               v = (red[t] + red[t + 128]) * (1.0f / S_);
        else if (k < D_ + NMOD)   v = rel[b * NMOD + (k - D_)];
        else if (k < RIN_)        v = reg[b * NREG + (k - D_ - NMOD)];
        rin[t] = v;
    }
    __syncthreads();
    int h = t & 127, half = t >> 7;
    float acc = 0.f;
#pragma unroll 8
    for (int i = 0; i < 64; ++i) {
        int kk = 2 * i + half;
        int k = k0 + kk;
        if (k < RIN_) acc += rin[kk] * w1[(size_t)k * HID_ + h];
    }
    red[t] = acc;
    __syncthreads();
    if (t < 128)
        hacc2[((size_t)b * KC_ + kc) * HID_ + t] = red[t] + red[t + 128];
}

__global__ void router_finish_kernel(const float* __restrict__ hacc2, const float* __restrict__ b1,
                                     const float* __restrict__ w2, const float* __restrict__ b2,
                                     int* __restrict__ top, float* __restrict__ bal_out) {
    __shared__ float h_lds[B_][HID_];
    __shared__ float logit[B_][E_];
    __shared__ float probs[B_][E_];
    int t = threadIdx.x; // 128
    for (int b = 0; b < B_; ++b) {
        float v = b1[t];
        for (int j = 0; j < KC_; ++j) v += hacc2[((size_t)b * KC_ + j) * HID_ + t];
        float u = 0.7978845608028654f * (v + 0.044715f * v * v * v); // tanh-GELU
        h_lds[b][t] = 0.5f * v * (1.0f + tanhf(u));
    }
    __syncthreads();
    if (t < B_ * E_) {
        int b = t >> 2, e = t & 3;
        float acc = b2[e];
        for (int j = 0; j < HID_; ++j) acc += h_lds[b][j] * w2[j * E_ + e];
        logit[b][e] = acc;
    }
    __syncthreads();
    if (t < B_) {
        int b = t;
        float mx = logit[b][0]; int arg = 0;
        for (int e = 1; e < E_; ++e) if (logit[b][e] > mx) { mx = logit[b][e]; arg = e; }
        float s = 0.f, pv[E_];
        for (int e = 0; e < E_; ++e) { pv[e] = expf(logit[b][e] - mx); s += pv[e]; }
        for (int e = 0; e < E_; ++e) probs[b][e] = pv[e] / s;
        top[b] = arg;
    }
    __syncthreads();
    if (t == 0) {
        float bal = 0.f;
        for (int e = 0; e < E_; ++e) {
            float avg = 0.25f * (probs[0][e] + probs[1][e] + probs[2][e] + probs[3][e]);
            bal += avg * avg;
        }
        *bal_out = 0.01f * E_ * bal;
    }
}

// Fused xr+out. Block (sb,b): 16 s-rows; 8 waves, wave w = K-slice [w*512,(w+1)*512).
// Phase 1 (NO barriers): wave-private LDS staging of bf16 x (no cvt; 2 int4/lane/iter);
// A frags coalesced from Apack. Reduce 8 slices (2 barriers).
// Phase 2: out[16 rows][w*512 ..+512) = xr_lds @ Bpack^T * 2, streamed.
__global__ __launch_bounds__(512) void xrout_kernel(const ushort* __restrict__ xbf,
                                                    const ushort* __restrict__ Apk,
                                                    const ushort* __restrict__ Bpk,
                                                    const int* __restrict__ top,
                                                    float* __restrict__ out) {
    __shared__ ushort xsw[8][16][70];   // wave-private x tiles (140B rows)
    __shared__ float  red[8][16][68];   // K-slice partials
    __shared__ ushort xs2[16][70];      // reduced xr tile, bf16
    int sb = blockIdx.x, b = blockIdx.y;
    int e  = top[b];
    int s0 = sb * 16;
    int t = threadIdx.x, l = t & 63, w = t >> 6;
    int kb = w * 512;

    // ---- phase 1: xr partial for all 16 rows, k in [kb, kb+512) ----
    const ushort* xb = xbf + ((size_t)b * S_ + s0) * D_;
    const int4*   ap = (const int4*)Apk + (size_t)e * 128 * 4 * 64 + l;
    f32x4 acc[4] = {};
    int row8 = l >> 3, c8 = l & 7;      // rows row8, row8+8 ; col-oct c8 (8 bf16 = 16B)
    for (int i = 0; i < 8; ++i) {
        int k0 = kb + i * 64;
        int4 xv0 = *(const int4*)(xb + (size_t)row8 * D_ + k0 + c8 * 8);
        int4 xv1 = *(const int4*)(xb + (size_t)(row8 + 8) * D_ + k0 + c8 * 8);
        *(int4*)&xsw[w][row8][c8 * 8]     = xv0;
        *(int4*)&xsw[w][row8 + 8][c8 * 8] = xv1;
        // frags: row l&15, k-cols kk*32+(l>>4)*8 (same-wave ds order via lgkmcnt)
#pragma unroll
        for (int kk = 0; kk < 2; ++kk) {
            short8 xf = *(const short8*)&xsw[w][l & 15][kk * 32 + (l >> 4) * 8];
            int ksg = w * 16 + i * 2 + kk;
#pragma unroll
            for (int n = 0; n < 4; ++n) {
                frag_u af; af.i4 = ap[((size_t)ksg * 4 + n) * 64];
                acc[n] = __builtin_amdgcn_mfma_f32_16x16x32_bf16(xf, af.s8, acc[n], 0, 0, 0);
            }
        }
    }
    // write K-slice partial (C/D layout: row (l>>4)*4+i, col n*16+(l&15))
#pragma unroll
    for (int n = 0; n < 4; ++n)
#pragma unroll
        for (int i = 0; i < 4; ++i)
            red[w][(l >> 4) * 4 + i][n * 16 + (l & 15)] = acc[n][i];
    __syncthreads();
    // reduce 8 K-slices -> bf16 xr tile (512 threads x 2 cols)
    {
        int rr = t >> 5, c2 = (t & 31) * 2;
        float s0f = red[0][rr][c2], s1f = red[0][rr][c2 + 1];
#pragma unroll
        for (int ks = 1; ks < 8; ++ks) {
            s0f += red[ks][rr][c2];
            s1f += red[ks][rr][c2 + 1];
        }
        xs2[rr][c2]     = f2bf(s0f);
        xs2[rr][c2 + 1] = f2bf(s1f);
    }
    __syncthreads();

    // ---- phase 2: out[16 rows][w*512 .. +512) = xr @ B^T * 2 ----
    short8 xf2[2];
#pragma unroll
    for (int kk = 0; kk < 2; ++kk)
        xf2[kk] = *(const short8*)&xs2[l & 15][kk * 32 + (l >> 4) * 8];
    const int4* bp = (const int4*)Bpk + (size_t)e * 256 * 2 * 64 + l;
    float* ob = out + ((size_t)b * S_ + s0) * OUT_ + w * 512;
    int ro = (l >> 4) * 4, co = l & 15;
#pragma unroll 4
    for (int ntl = 0; ntl < 32; ++ntl) {
        int nt = w * 32 + ntl;
        frag_u bf0, bf1;
        bf0.i4 = bp[((size_t)nt * 2 + 0) * 64];
        bf1.i4 = bp[((size_t)nt * 2 + 1) * 64];
        f32x4 a2 = {};
        a2 = __builtin_amdgcn_mfma_f32_16x16x32_bf16(xf2[0], bf0.s8, a2, 0, 0, 0);
        a2 = __builtin_amdgcn_mfma_f32_16x16x32_bf16(xf2[1], bf1.s8, a2, 0, 0, 0);
#pragma unroll
        for (int i = 0; i < 4; ++i)
            ob[(size_t)(ro + i) * OUT_ + ntl * 16 + co] = a2[i] * SCALING_;
    }
}

extern "C" void kernel_launch(void* const* d_in, const int* in_sizes, int n_in,
                              void* d_out, int out_size, void* d_ws, size_t ws_size,
                              hipStream_t stream) {
    const float* x   = (const float*)d_in[0];
    const float* rel = (const float*)d_in[1];
    const float* reg = (const float*)d_in[2];
    const float* lA  = (const float*)d_in[3];
    const float* lB  = (const float*)d_in[4];
    const float* w1  = (const float*)d_in[5];
    const float* b1  = (const float*)d_in[6];
    const float* w2  = (const float*)d_in[7];
    const float* b2  = (const float*)d_in[8];
    float* out = (float*)d_out;
    float* ws  = (float*)d_ws;

    float*  pp    = ws + WS_PP;
    float*  hacc2 = ws + WS_HACC2;
    int*    top   = (int*)(ws + WS_TOP);
    ushort* Apk   = (ushort*)(ws + WS_APK);
    ushort* Bpk   = (ushort*)(ws + WS_BPK);
    ushort* xbf   = (ushort*)(ws + WS_XBF);

    prep_kernel<<<2048, 256, 0, stream>>>(x, lA, lB, pp, Apk, Bpk, xbf);
    router_h_kernel<<<dim3(B_, KC_), 256, 0, stream>>>(pp, rel, reg, w1, hacc2);
    router_finish_kernel<<<1, 128, 0, stream>>>(hacc2, b1, w2, b2, top,
                                                out + (size_t)out_size - 1);
    xrout_kernel<<<dim3(S_ / 16, B_), 512, 0, stream>>>(xbf, Apk, Bpk, top, out);
}

// Round 21
// 109.224 us; speedup vs baseline: 1.3879x; 1.3879x over previous
//
#include <hip/hip_runtime.h>

// MoE-LoRA top-1 dispatch — R14 structure, prep split for attribution:
//  pool (pure x stream) | pack (A/B frag gather) -> router_h -> router_finish
//  -> xrout (x@A^T -> in-LDS xr -> @B^T -> out, fused, 16-row blocks)
constexpr int B_ = 4, S_ = 2048, D_ = 4096, E_ = 4, R_ = 64, OUT_ = 4096;
constexpr int NMOD = 4, NREG = 3, HID_ = 128;
constexpr int RIN_ = D_ + NMOD + NREG;      // 4103
constexpr float SCALING_ = 2.0f;            // alpha/rank
constexpr int P_   = 128;                   // pool strips of 16 rows
constexpr int KC_  = 33;                    // router k-chunks of 128 (33*128 >= 4103)

// ws layout (float units)
constexpr size_t WS_PP    = 0;                                     // P_*B*D f32 pool partials
constexpr size_t WS_HACC2 = WS_PP + (size_t)P_ * B_ * D_;          // B*KC_*HID f32
constexpr size_t WS_TOP   = WS_HACC2 + B_ * KC_ * HID_;            // B ints
constexpr size_t WS_APK   = WS_TOP + 16;                           // E*R*D bf16 frag-packed
constexpr size_t WS_BPK   = WS_APK + (size_t)E_ * R_ * D_ / 2;     // E*OUT*R bf16 frag-packed

using short8 = __attribute__((ext_vector_type(8))) short;
using f32x4  = __attribute__((ext_vector_type(4))) float;
union frag_u { int4 i4; short8 s8; };

__device__ inline unsigned short f2bf(float f) {  // RNE fp32 -> bf16
    unsigned u = __float_as_uint(f);
    unsigned r = u + 0x7FFFu + ((u >> 16) & 1u);
    return (unsigned short)(r >> 16);
}

// Pure x stream: pool partials, strip = bx>>2 (16 rows), b = bx&3
__global__ __launch_bounds__(256) void pool_kernel(const float* __restrict__ x,
                                                   float* __restrict__ pp) {
    int bx = blockIdx.x, t = threadIdx.x;
    int strip = bx >> 2, b = bx & 3;
    const float4* xp = (const float4*)(x + ((size_t)b * S_ + strip * 16) * D_);
    float4 a0 = {0,0,0,0}, a1 = {0,0,0,0}, a2 = {0,0,0,0}, a3 = {0,0,0,0};
#pragma unroll 4
    for (int r = 0; r < 16; ++r) {
        float4 v0 = xp[(size_t)r * 1024 + t];
        float4 v1 = xp[(size_t)r * 1024 + 256 + t];
        float4 v2 = xp[(size_t)r * 1024 + 512 + t];
        float4 v3 = xp[(size_t)r * 1024 + 768 + t];
        a0.x += v0.x; a0.y += v0.y; a0.z += v0.z; a0.w += v0.w;
        a1.x += v1.x; a1.y += v1.y; a1.z += v1.z; a1.w += v1.w;
        a2.x += v2.x; a2.y += v2.y; a2.z += v2.z; a2.w += v2.w;
        a3.x += v3.x; a3.y += v3.y; a3.z += v3.z; a3.w += v3.w;
    }
    float* ppb = pp + ((size_t)strip * B_ + b) * D_;
    *(float4*)&ppb[(t)       * 4] = a0;
    *(float4*)&ppb[(256 + t) * 4] = a1;
    *(float4*)&ppb[(512 + t) * 4] = a2;
    *(float4*)&ppb[(768 + t) * 4] = a3;
}

// A/B frag-pack gather:
//  [0,512):    Apack[((e*128+ks)*4+n)*64+l][j] = A[e][n*16+(l&15)][ks*32+(l>>4)*8+j]
//  [512,1024): Bpack[((e*256+nt)*2+kk)*64+l][j] = B[e][nt*16+(l&15)][kk*32+(l>>4)*8+j]
__global__ __launch_bounds__(256) void pack_kernel(const float* __restrict__ A,
                                                   const float* __restrict__ Bw,
                                                   ushort* __restrict__ Apk,
                                                   ushort* __restrict__ Bpk) {
    int bx = blockIdx.x, t = threadIdx.x;
    if (bx < 512) {
        int idx = bx * 256 + t;                      // E*128*4*64 = 131072
        int l = idx & 63, n = (idx >> 6) & 3, ks = (idx >> 8) & 127, e = idx >> 15;
        const float* src = A + ((size_t)e * R_ + n * 16 + (l & 15)) * D_
                             + ks * 32 + (l >> 4) * 8;
        float4 v0 = *(const float4*)(src);
        float4 v1 = *(const float4*)(src + 4);
        ushort* dst = Apk + (size_t)idx * 8;
        *(ushort4*)(dst)     = make_ushort4(f2bf(v0.x), f2bf(v0.y), f2bf(v0.z), f2bf(v0.w));
        *(ushort4*)(dst + 4) = make_ushort4(f2bf(v1.x), f2bf(v1.y), f2bf(v1.z), f2bf(v1.w));
    } else {
        int idx = (bx - 512) * 256 + t;              // E*256*2*64 = 131072
        int l = idx & 63, kk = (idx >> 6) & 1, nt = (idx >> 7) & 255, e = idx >> 15;
        const float* src = Bw + ((size_t)e * OUT_ + nt * 16 + (l & 15)) * R_
                              + kk * 32 + (l >> 4) * 8;
        float4 v0 = *(const float4*)(src);
        float4 v1 = *(const float4*)(src + 4);
        ushort* dst = Bpk + (size_t)idx * 8;
        *(ushort4*)(dst)     = make_ushort4(f2bf(v0.x), f2bf(v0.y), f2bf(v0.z), f2bf(v0.w));
        *(ushort4*)(dst + 4) = make_ushort4(f2bf(v1.x), f2bf(v1.y), f2bf(v1.z), f2bf(v1.w));
    }
}

// hacc2[b][kc][h] = sum over chunk's 128 k-rows of router_in[k]*w1[k][h]
__global__ __launch_bounds__(256) void router_h_kernel(const float* __restrict__ pp,
                                                       const float* __restrict__ rel,
                                                       const float* __restrict__ reg,
                                                       const float* __restrict__ w1,
                                                       float* __restrict__ hacc2) {
    __shared__ float rin[128];
    __shared__ float red[256];
    int b = blockIdx.x, kc = blockIdx.y;
    int t = threadIdx.x;
    int k0 = kc * 128;
    {
        int k = k0 + (t & 127), half = t >> 7;
        float s = 0.f;
        if (k < D_) {
            for (int pi = half * 64; pi < half * 64 + 64; ++pi)
                s += pp[((size_t)pi * B_ + b) * D_ + k];
        }
        red[t] = s;
    }
    __syncthreads();
    if (t < 128) {
        int k = k0 + t;
        float v = 0.f;
        if (k < D_)               v = (red[t] + red[t + 128]) * (1.0f / S_);
        else if (k < D_ + NMOD)   v = rel[b * NMOD + (k - D_)];
        else if (k < RIN_)        v = reg[b * NREG + (k - D_ - NMOD)];
        rin[t] = v;
    }
    __syncthreads();
    int h = t & 127, half = t >> 7;
    float acc = 0.f;
#pragma unroll 8
    for (int i = 0; i < 64; ++i) {
        int kk = 2 * i + half;
        int k = k0 + kk;
        if (k < RIN_) acc += rin[kk] * w1[(size_t)k * HID_ + h];
    }
    red[t] = acc;
    __syncthreads();
    if (t < 128)
        hacc2[((size_t)b * KC_ + kc) * HID_ + t] = red[t] + red[t + 128];
}

__global__ void router_finish_kernel(const float* __restrict__ hacc2, const float* __restrict__ b1,
                                     const float* __restrict__ w2, const float* __restrict__ b2,
                                     int* __restrict__ top, float* __restrict__ bal_out) {
    __shared__ float h_lds[B_][HID_];
    __shared__ float logit[B_][E_];
    __shared__ float probs[B_][E_];
    int t = threadIdx.x; // 128
    for (int b = 0; b < B_; ++b) {
        float v = b1[t];
        for (int j = 0; j < KC_; ++j) v += hacc2[((size_t)b * KC_ + j) * HID_ + t];
        float u = 0.7978845608028654f * (v + 0.044715f * v * v * v); // tanh-GELU
        h_lds[b][t] = 0.5f * v * (1.0f + tanhf(u));
    }
    __syncthreads();
    if (t < B_ * E_) {
        int b = t >> 2, e = t & 3;
        float acc = b2[e];
        for (int j = 0; j < HID_; ++j) acc += h_lds[b][j] * w2[j * E_ + e];
        logit[b][e] = acc;
    }
    __syncthreads();
    if (t < B_) {
        int b = t;
        float mx = logit[b][0]; int arg = 0;
        for (int e = 1; e < E_; ++e) if (logit[b][e] > mx) { mx = logit[b][e]; arg = e; }
        float s = 0.f, pv[E_];
        for (int e = 0; e < E_; ++e) { pv[e] = expf(logit[b][e] - mx); s += pv[e]; }
        for (int e = 0; e < E_; ++e) probs[b][e] = pv[e] / s;
        top[b] = arg;
    }
    __syncthreads();
    if (t == 0) {
        float bal = 0.f;
        for (int e = 0; e < E_; ++e) {
            float avg = 0.25f * (probs[0][e] + probs[1][e] + probs[2][e] + probs[3][e]);
            bal += avg * avg;
        }
        *bal_out = 0.01f * E_ * bal;
    }
}

// Fused xr+out. Block (sb,b): 16 s-rows; 8 waves, wave w = K-slice [w*512,(w+1)*512).
// Phase 1 (NO barriers): wave-private LDS x-staging; A frags coalesced from Apack;
// each wave accumulates all 4 n-tiles over its K-slice. Reduce 8 slices (2 barriers).
// Phase 2: out[16 rows][w*512 ..+512) = xr_lds @ Bpack^T * 2, streamed.
__global__ __launch_bounds__(512) void xrout_kernel(const float* __restrict__ x,
                                                    const ushort* __restrict__ Apk,
                                                    const ushort* __restrict__ Bpk,
                                                    const int* __restrict__ top,
                                                    float* __restrict__ out) {
    __shared__ ushort xsw[8][16][70];   // wave-private x tiles (140B rows)
    __shared__ float  red[8][16][68];   // K-slice partials
    __shared__ ushort xs2[16][70];      // reduced xr tile, bf16
    int sb = blockIdx.x, b = blockIdx.y;
    int e  = top[b];
    int s0 = sb * 16;
    int t = threadIdx.x, l = t & 63, w = t >> 6;
    int kb = w * 512;

    // ---- phase 1: xr partial for all 16 rows, k in [kb, kb+512) ----
    const float* xb = x + ((size_t)b * S_ + s0) * D_;
    const int4*  ap = (const int4*)Apk + (size_t)e * 128 * 4 * 64 + l;
    f32x4 acc[4] = {};
    int lr = l >> 4, lc = l & 15;       // load: rows lr+4j, col-quad lc
    for (int i = 0; i < 8; ++i) {
        int k0 = kb + i * 64;
        float4 xv[4];
#pragma unroll
        for (int j = 0; j < 4; ++j)
            xv[j] = *(const float4*)(xb + (size_t)(lr + 4 * j) * D_ + k0 + lc * 4);
#pragma unroll
        for (int j = 0; j < 4; ++j)
            *(ushort4*)&xsw[w][lr + 4 * j][lc * 4] =
                make_ushort4(f2bf(xv[j].x), f2bf(xv[j].y), f2bf(xv[j].z), f2bf(xv[j].w));
        // frags: row l&15, k-cols kk*32+(l>>4)*8 (same-wave ds order via lgkmcnt)
#pragma unroll
        for (int kk = 0; kk < 2; ++kk) {
            short8 xf = *(const short8*)&xsw[w][l & 15][kk * 32 + (l >> 4) * 8];
            int ksg = w * 16 + i * 2 + kk;
#pragma unroll
            for (int n = 0; n < 4; ++n) {
                frag_u af; af.i4 = ap[((size_t)ksg * 4 + n) * 64];
                acc[n] = __builtin_amdgcn_mfma_f32_16x16x32_bf16(xf, af.s8, acc[n], 0, 0, 0);
            }
        }
    }
    // write K-slice partial (C/D layout: row (l>>4)*4+i, col n*16+(l&15))
#pragma unroll
    for (int n = 0; n < 4; ++n)
#pragma unroll
        for (int i = 0; i < 4; ++i)
            red[w][(l >> 4) * 4 + i][n * 16 + (l & 15)] = acc[n][i];
    __syncthreads();
    // reduce 8 K-slices -> bf16 xr tile (512 threads x 2 cols)
    {
        int row = t >> 5, c2 = (t & 31) * 2;
        float s0f = red[0][row][c2], s1f = red[0][row][c2 + 1];
#pragma unroll
        for (int ks = 1; ks < 8; ++ks) {
            s0f += red[ks][row][c2];
            s1f += red[ks][row][c2 + 1];
        }
        xs2[row][c2]     = f2bf(s0f);
        xs2[row][c2 + 1] = f2bf(s1f);
    }
    __syncthreads();

    // ---- phase 2: out[16 rows][w*512 .. +512) = xr @ B^T * 2 ----
    short8 xf2[2];
#pragma unroll
    for (int kk = 0; kk < 2; ++kk)
        xf2[kk] = *(const short8*)&xs2[l & 15][kk * 32 + (l >> 4) * 8];
    const int4* bp = (const int4*)Bpk + (size_t)e * 256 * 2 * 64 + l;
    float* ob = out + ((size_t)b * S_ + s0) * OUT_ + w * 512;
    int ro = (l >> 4) * 4, co = l & 15;
#pragma unroll 4
    for (int ntl = 0; ntl < 32; ++ntl) {
        int nt = w * 32 + ntl;
        frag_u bf0, bf1;
        bf0.i4 = bp[((size_t)nt * 2 + 0) * 64];
        bf1.i4 = bp[((size_t)nt * 2 + 1) * 64];
        f32x4 a2 = {};
        a2 = __builtin_amdgcn_mfma_f32_16x16x32_bf16(xf2[0], bf0.s8, a2, 0, 0, 0);
        a2 = __builtin_amdgcn_mfma_f32_16x16x32_bf16(xf2[1], bf1.s8, a2, 0, 0, 0);
#pragma unroll
        for (int i = 0; i < 4; ++i)
            ob[(size_t)(ro + i) * OUT_ + ntl * 16 + co] = a2[i] * SCALING_;
    }
}

extern "C" void kernel_launch(void* const* d_in, const int* in_sizes, int n_in,
                              void* d_out, int out_size, void* d_ws, size_t ws_size,
                              hipStream_t stream) {
    const float* x   = (const float*)d_in[0];
    const float* rel = (const float*)d_in[1];
    const float* reg = (const float*)d_in[2];
    const float* lA  = (const float*)d_in[3];
    const float* lB  = (const float*)d_in[4];
    const float* w1  = (const float*)d_in[5];
    const float* b1  = (const float*)d_in[6];
    const float* w2  = (const float*)d_in[7];
    const float* b2  = (const float*)d_in[8];
    float* out = (float*)d_out;
    float* ws  = (float*)d_ws;

    float*  pp    = ws + WS_PP;
    float*  hacc2 = ws + WS_HACC2;
    int*    top   = (int*)(ws + WS_TOP);
    ushort* Apk   = (ushort*)(ws + WS_APK);
    ushort* Bpk   = (ushort*)(ws + WS_BPK);

    pool_kernel<<<512, 256, 0, stream>>>(x, pp);
    pack_kernel<<<1024, 256, 0, stream>>>(lA, lB, Apk, Bpk);
    router_h_kernel<<<dim3(B_, KC_), 256, 0, stream>>>(pp, rel, reg, w1, hacc2);
    router_finish_kernel<<<1, 128, 0, stream>>>(hacc2, b1, w2, b2, top,
                                                out + (size_t)out_size - 1);
    xrout_kernel<<<dim3(S_ / 16, B_), 512, 0, stream>>>(x, Apk, Bpk, top, out);
}